// Round 23
// baseline (397.205 us; speedup 1.0000x reference)
//
#include <hip/hip_runtime.h>
#include <cstdint>

#define AS1 __attribute__((address_space(1)))
#define AS3 __attribute__((address_space(3)))

typedef __bf16 bf16x8 __attribute__((ext_vector_type(8)));
typedef __bf16 bf16x4 __attribute__((ext_vector_type(4)));
typedef float  f32x4  __attribute__((ext_vector_type(4)));

// Per-batch element strides
#define XB_STRIDE   4194304ul   // 4096*1024 bf16 (also Qb, Kb, Vt, input-slice fp32)
#define SCH_STRIDE  16777216ul  // 4096*4096 bf16 E matrix per batch
#define OUT_STRIDE  8388608ul   // 2048*4096 fp32

// ---------------------------------------------------------------------------
// SOFTMAX (r22 exp-direct + r23 fused rowsum): qk's epilogue writes
// E = exp(s - sig|df|) bf16 (masked -> 0; no max-subtraction needed since
// scores are bounded above and bf16 has fp32 range), AND accumulates the
// per-row sum L via 16-lane shfl reduction + one fp32 atomicAdd per
// (row, wave, tile). pv divides its fp32 acc by L[row]. E/L == softmax
// exactly. The separate rowsum pass (68MB re-read) is deleted.
// ---------------------------------------------------------------------------

// input slice [1024][4096] fp32 -> xb [4096][1024] bf16 (tiled transpose),
// FUSED with the fp32 identity copy into the output top-half (r15-verified).
__global__ void transpose_x_k(const float* __restrict__ in, __bf16* __restrict__ out,
                              float* __restrict__ outtop) {
  in     += (size_t)blockIdx.z * XB_STRIDE;
  out    += (size_t)blockIdx.z * XB_STRIDE;
  outtop += (size_t)blockIdx.z * OUT_STRIDE;
  __shared__ float t[32][33];
  int s0 = blockIdx.x * 32, c0 = blockIdx.y * 32;
  int tx = threadIdx.x, ty = threadIdx.y;
#pragma unroll
  for (int i = 0; i < 4; i++) {
    int idx = (c0 + ty + i * 8) * 4096 + s0 + tx;
    float v = in[idx];
    t[ty + i * 8][tx] = v;
    outtop[idx] = v;                   // fp32 passthrough to out[b][c][s], c<1024
  }
  __syncthreads();
#pragma unroll
  for (int i = 0; i < 4; i++)
    out[(s0 + ty + i * 8) * 1024 + c0 + tx] = (__bf16)t[tx][ty + i * 8];
}

// Wq/Wk/Wv [1024][1024] fp32 -> Wt [3072][1024] bf16 transposed, Q slice pre-scaled 1/32
__global__ void transpose_w_k(const float* __restrict__ Wq, const float* __restrict__ Wk,
                              const float* __restrict__ Wv, __bf16* __restrict__ Wt) {
  __shared__ float t[32][33];
  int sel = blockIdx.z;
  const float* W = sel == 0 ? Wq : (sel == 1 ? Wk : Wv);
  float scale = sel == 0 ? 0.03125f : 1.0f;
  int n0 = blockIdx.x * 32, c0 = blockIdx.y * 32;
  int tx = threadIdx.x, ty = threadIdx.y;
#pragma unroll
  for (int i = 0; i < 4; i++)
    t[ty + i * 8][tx] = W[(c0 + ty + i * 8) * 1024 + n0 + tx];
  __syncthreads();
#pragma unroll
  for (int i = 0; i < 4; i++)
    Wt[(sel * 1024 + n0 + ty + i * 8) * 1024 + c0 + tx] = (__bf16)(t[tx][ty + i * 8] * scale);
}

__global__ void bcat_k(const float* __restrict__ bq, const float* __restrict__ bk,
                       const float* __restrict__ bv, float* __restrict__ bcat) {
  int n = blockIdx.x * 256 + threadIdx.x;       // 3072 total
  float v = n < 1024 ? bq[n] * 0.03125f : (n < 2048 ? bk[n - 1024] : bv[n - 2048]);
  bcat[n] = v;
}

// L[z][row] = 0 (atomic accumulator reset; ws is not re-poisoned by harness)
__global__ void zeroL_k(float* __restrict__ L) {
  L[(size_t)blockIdx.y * 4096 + blockIdx.x * 1024 + threadIdx.x] = 0.0f;
}

// ---------------------------------------------------------------------------
// 256x256 BK=64 streaming GEMM core (round 10; bank-conflict-free swizzle,
// counted vmcnt, 2 barriers/K-tile). Unchanged.
// ---------------------------------------------------------------------------
template<int MH, int NH>
__device__ __forceinline__ void mf_quad(f32x4 (&acc)[8][4], bf16x8 (&aR)[4][2],
                                        bf16x8 (&br)[2][2]) {
#pragma unroll
  for (int q = 0; q < 4; q++)
#pragma unroll
    for (int r = 0; r < 2; r++) {
      acc[MH * 4 + q][NH * 2 + r] = __builtin_amdgcn_mfma_f32_16x16x32_bf16(
          aR[q][0], br[r][0], acc[MH * 4 + q][NH * 2 + r], 0, 0, 0);
      acc[MH * 4 + q][NH * 2 + r] = __builtin_amdgcn_mfma_f32_16x16x32_bf16(
          aR[q][1], br[r][1], acc[MH * 4 + q][NH * 2 + r], 0, 0, 0);
    }
}

__device__ __forceinline__ void gemm256_core(const __bf16* __restrict__ A, int lda, int m0,
                                             const __bf16* __restrict__ B, int ldb, int n0,
                                             __bf16* lds, f32x4 (&acc)[8][4]) {
  const int tid = threadIdx.x;
  const int l = tid & 63;
  const int w = tid >> 6;
  const int wm = w >> 2, wn = w & 3;
  const int lr = l & 15, kg = l >> 4;
  const int lrow = l >> 3;
  const int scol = ((l & 7) ^ lrow) << 3;
  const int xorv = (lr & 7) << 4;
  const int cc0 = (kg << 4) ^ xorv;
  const int cc1 = (64 | (kg << 4)) ^ xorv;
  const int ch = w * 2;
  const char* ldsA = (const char*)lds + wm * 16384;
  const char* ldsB = (const char*)lds + 32768 + (wn >> 1) * 16384;
  const int browb = (wn & 1) * 64;

#define STG8(PTR, LD, BASE0, H, TT, JB, OPOFF) do {                                              \
    const __bf16* sp_ = (PTR) + (size_t)((BASE0) + (H) * 128 + ch * 8 + lrow) * (LD) +           \
                        (TT) * 64 + scol;                                                        \
    __bf16* dp_ = lds + ((JB) * 32768 + (OPOFF) + (H) * 8192 + ch * 512);                        \
    __builtin_amdgcn_global_load_lds((const AS1 void*)sp_,                   (AS3 void*)dp_,         16, 0, 0); \
    __builtin_amdgcn_global_load_lds((const AS1 void*)(sp_ + (size_t)8 * (LD)), (AS3 void*)(dp_ + 512), 16, 0, 0); \
  } while (0)
#define STGA(H, TT, JB) STG8(A, lda, m0, H, TT, JB, 0)
#define STGB(H, TT, JB) STG8(B, ldb, n0, H, TT, JB, 16384)
#define LDAF(dst, MH_, Q_) do {                                                                  \
    const char* p_ = ldsA + jbyte + ((MH_) * 64 + (Q_) * 16 + lr) * 128;                         \
    (dst)[0] = *(const bf16x8*)(p_ + cc0);                                                       \
    (dst)[1] = *(const bf16x8*)(p_ + cc1);                                                       \
  } while (0)
#define LDBF(dst, NH_, R_) do {                                                                  \
    const char* p_ = ldsB + jbyte + (browb + ((NH_) * 2 + (R_)) * 16 + lr) * 128;                \
    (dst)[0] = *(const bf16x8*)(p_ + cc0);                                                       \
    (dst)[1] = *(const bf16x8*)(p_ + cc1);                                                       \
  } while (0)

  STGA(0, 0, 0); STGA(1, 0, 0); STGB(0, 0, 0); STGB(1, 0, 0);
  STGB(0, 1, 1); STGA(0, 1, 1);
  asm volatile("s_waitcnt vmcnt(4)" ::: "memory");
  __builtin_amdgcn_sched_barrier(0);
  __builtin_amdgcn_s_barrier();

  bf16x8 aR[4][2], b0r[2][2], b1r[2][2];
  for (int t = 0; t < 16; ++t) {
    const int j = t & 1, jo = j ^ 1;
    const int jbyte = j * 65536;

#pragma unroll
    for (int q = 0; q < 4; q++) LDAF(aR[q], 0, q);
#pragma unroll
    for (int r = 0; r < 2; r++) LDBF(b0r[r], 0, r);
#pragma unroll
    for (int r = 0; r < 2; r++) LDBF(b1r[r], 1, r);
    if (t < 15) { STGA(1, t + 1, jo); STGB(1, t + 1, jo); }

    __builtin_amdgcn_s_setprio(1);
    mf_quad<0, 0>(acc, aR, b0r);
    mf_quad<0, 1>(acc, aR, b1r);
    __builtin_amdgcn_s_setprio(0);

#pragma unroll
    for (int q = 0; q < 4; q++) LDAF(aR[q], 1, q);
    __builtin_amdgcn_s_setprio(1);
    mf_quad<1, 1>(acc, aR, b1r);
    __builtin_amdgcn_s_setprio(0);

    asm volatile("s_waitcnt lgkmcnt(0)" ::: "memory");
    __builtin_amdgcn_sched_barrier(0);
    __builtin_amdgcn_s_barrier();
    if (t < 14) { STGB(0, t + 2, j); STGA(0, t + 2, j); }

    __builtin_amdgcn_s_setprio(1);
    mf_quad<1, 0>(acc, aR, b0r);
    __builtin_amdgcn_s_setprio(0);

    if (t < 14) asm volatile("s_waitcnt vmcnt(4)" ::: "memory");
    else        asm volatile("s_waitcnt vmcnt(0)" ::: "memory");
    __builtin_amdgcn_sched_barrier(0);
    __builtin_amdgcn_s_barrier();
  }
#undef STG8
#undef STGA
#undef STGB
#undef LDAF
#undef LDBF
}

// ---------------------------------------------------------------------------
// QKV fused projection (batched z), 256x256 streaming: [4096 x 3072] = xb @ Wt^T
__global__ void __launch_bounds__(512, 1)
qkv_gemm_k(const __bf16* __restrict__ xb, const __bf16* __restrict__ Wt,
           const float* __restrict__ bcat, __bf16* __restrict__ Qb,
           __bf16* __restrict__ Kb, __bf16* __restrict__ Vt) {
  size_t zo = (size_t)blockIdx.z * XB_STRIDE;
  xb += zo; Qb += zo; Kb += zo; Vt += zo;
  __shared__ __bf16 lds[65536];   // 128 KB
  f32x4 acc[8][4] = {};
  int m0 = blockIdx.y * 256, n0 = blockIdx.x * 256;
  gemm256_core(xb, 1024, m0, Wt, 1024, n0, lds, acc);

  const int l = threadIdx.x & 63;
  const int w = threadIdx.x >> 6;
  const int wm = w >> 2, wn = w & 3;
  const int lr = l & 15;
  const int lg = (l >> 4) * 4;
#pragma unroll
  for (int am = 0; am < 8; am++) {
    int rs = m0 + wm * 128 + am * 16 + lg;
#pragma unroll
    for (int an = 0; an < 4; an++) {
      int col = n0 + wn * 64 + an * 16 + lr;
      float bias = bcat[col];
      if (col < 1024) {
#pragma unroll
        for (int r = 0; r < 4; r++)
          Qb[(rs + r) * 1024 + col] = (__bf16)(acc[am][an][r] + bias);
      } else if (col < 2048) {
#pragma unroll
        for (int r = 0; r < 4; r++)
          Kb[(rs + r) * 1024 + (col - 1024)] = (__bf16)(acc[am][an][r] + bias);
      } else {
        bf16x4 t4;
#pragma unroll
        for (int r = 0; r < 4; r++) t4[r] = (__bf16)(acc[am][an][r] + bias);
        *(bf16x4*)(Vt + (size_t)(col - 2048) * 4096 + rs) = t4;
      }
    }
  }
}

// ---------------------------------------------------------------------------
// QK^T + exp-direct numerator + fused row-sum (batched z): epilogue applies
// causal mask + alibi, writes E = exp(s - sig|df|) bf16 (masked -> 0), then
// reduces each row's 64-col slice across the 16 lr lanes (shfl_xor 1,2,4,8 --
// stays within the l>>4 group) and atomicAdds one fp32 per (row, wave, tile)
// into L. Upper-tri 256-tiles skipped.
__global__ void __launch_bounds__(512, 1)
qk_gemm_k(const __bf16* __restrict__ Qb, const __bf16* __restrict__ Kb,
          __bf16* __restrict__ Eb, float* __restrict__ L,
          const float* __restrict__ frame, const float* __restrict__ alibi_p) {
  if (blockIdx.x > blockIdx.y) return;
  size_t zo = (size_t)blockIdx.z * XB_STRIDE;
  Qb += zo; Kb += zo;
  Eb += (size_t)blockIdx.z * SCH_STRIDE;
  L  += (size_t)blockIdx.z * 4096;
  __shared__ __bf16 lds[65536];   // 128 KB
  f32x4 acc[8][4] = {};
  int m0 = blockIdx.y * 256, n0 = blockIdx.x * 256;
  gemm256_core(Qb, 1024, m0, Kb, 1024, n0, lds, acc);

  const int l = threadIdx.x & 63;
  const int w = threadIdx.x >> 6;
  const int wm = w >> 2, wn = w & 3;
  const int lr = l & 15;
  const int lg = (l >> 4) * 4;
  float sig = 1.0f / (1.0f + __expf(-alibi_p[0]));
  float fc[4];
#pragma unroll
  for (int an = 0; an < 4; an++) fc[an] = frame[n0 + wn * 64 + an * 16 + lr];
#pragma unroll
  for (int am = 0; am < 8; am++) {
    int rs = m0 + wm * 128 + am * 16 + lg;
    float frr[4] = {frame[rs], frame[rs + 1], frame[rs + 2], frame[rs + 3]};
    float ps[4] = {0.0f, 0.0f, 0.0f, 0.0f};
#pragma unroll
    for (int an = 0; an < 4; an++) {
      int col = n0 + wn * 64 + an * 16 + lr;
#pragma unroll
      for (int r = 0; r < 4; r++) {
        int row = rs + r;
        float e = (col <= row) ? __expf(acc[am][an][r] - sig * fabsf(fc[an] - frr[r])) : 0.0f;
        Eb[(size_t)row * 4096 + col] = (__bf16)e;
        ps[r] += e;
      }
    }
#pragma unroll
    for (int r = 0; r < 4; r++) {
#pragma unroll
      for (int o = 8; o; o >>= 1) ps[r] += __shfl_xor(ps[r], o, 64);
    }
    if (lr == 0) {
#pragma unroll
      for (int r = 0; r < 4; r++) atomicAdd(&L[rs + r], ps[r]);
    }
  }
}

// ---------------------------------------------------------------------------
// 128x128 depth-2 pipelined core (round-6), kept for PV.
__device__ __forceinline__ void gemm128_core(const __bf16* __restrict__ A, int lda, int m0,
                                             const __bf16* __restrict__ B, int ldb, int n0,
                                             int nt, __bf16 (*As)[4096], __bf16 (*Bs)[4096],
                                             f32x4 acc[4][4]) {
  const int tid = threadIdx.x;
  const int lane = tid & 63;
  const int wid = tid >> 6;
  const int wr = wid >> 1, wc = wid & 1;
  const int lr = lane & 15;
  const int lk = (((lane >> 4) ^ (lane & 3)) << 3);
  const int srow = tid >> 2;
  const int skq = (((tid & 3) ^ (srow & 3)) << 3);
  const __bf16* ga = A + (long)(m0 + srow) * lda + skq;
  const __bf16* gb = B + (long)(n0 + srow) * ldb + skq;

#define STAGE(t, j) do {                                                                                             \
    int k0_ = (t) * 32;                                                                                              \
    __builtin_amdgcn_global_load_lds((const AS1 void*)(ga + k0_),            (AS3 void*)(As[j] + tid * 8),        16, 0, 0); \
    __builtin_amdgcn_global_load_lds((const AS1 void*)(ga + k0_ + 64 * lda), (AS3 void*)(As[j] + tid * 8 + 2048), 16, 0, 0); \
    __builtin_amdgcn_global_load_lds((const AS1 void*)(gb + k0_),            (AS3 void*)(Bs[j] + tid * 8),        16, 0, 0); \
    __builtin_amdgcn_global_load_lds((const AS1 void*)(gb + k0_ + 64 * ldb), (AS3 void*)(Bs[j] + tid * 8 + 2048), 16, 0, 0); \
  } while (0)

  STAGE(0, 0);
  if (nt > 1) STAGE(1, 1);

  for (int t = 0; t < nt; ++t) {
    const int j = t & 1;
    if (t + 1 < nt) asm volatile("s_waitcnt vmcnt(4)" ::: "memory");
    else            asm volatile("s_waitcnt vmcnt(0)" ::: "memory");
    __builtin_amdgcn_s_barrier();
    __builtin_amdgcn_sched_barrier(0);

    bf16x8 af[4], bfr[4];
#pragma unroll
    for (int m = 0; m < 4; m++)
      af[m] = *(const bf16x8*)(As[j] + (wr * 64 + m * 16 + lr) * 32 + lk);
#pragma unroll
    for (int n = 0; n < 4; n++)
      bfr[n] = *(const bf16x8*)(Bs[j] + (wc * 64 + n * 16 + lr) * 32 + lk);
#pragma unroll
    for (int m = 0; m < 4; m++)
#pragma unroll
      for (int n = 0; n < 4; n++)
        acc[m][n] = __builtin_amdgcn_mfma_f32_16x16x32_bf16(af[m], bfr[n], acc[m][n], 0, 0, 0);

    asm volatile("s_waitcnt lgkmcnt(0)" ::: "memory");
    __builtin_amdgcn_sched_barrier(0);
    __builtin_amdgcn_s_barrier();
    __builtin_amdgcn_sched_barrier(0);
    if (t + 2 < nt) STAGE(t + 2, j);
  }
#undef STAGE
}

// ---------------------------------------------------------------------------
// PV (batched z): out[v][s] = (1/L_s) * sum_{t<=s} E[s,t] * Vt[v,t]; 128^2
// core; 1/L applied to the fp32 acc in the epilogue (exact softmax).
// Grid (32, 8, z): XCD grouping + depth reflection (round-9 win). E stride 4096.
__global__ void pv_gemm_k(const __bf16* __restrict__ E, const __bf16* __restrict__ Vt,
                          const float* __restrict__ L, float* __restrict__ outb) {
  int z = blockIdx.z;
  int mi = (z & 1) ? blockIdx.x : 31 - blockIdx.x;   // depth reflection
  int n0 = blockIdx.y * 128;
  E    += (size_t)z * SCH_STRIDE;
  Vt   += (size_t)z * XB_STRIDE;
  L    += (size_t)z * 4096;
  outb += (size_t)z * OUT_STRIDE;
  __shared__ __bf16 As[2][4096], Bs[2][4096];
  f32x4 acc[4][4] = {};
  int m0 = mi * 128;
  gemm128_core(E, 4096, m0, Vt, 4096, n0, (m0 + 128) / 32, As, Bs, acc);

  const int lane = threadIdx.x & 63;
  const int wid = threadIdx.x >> 6;
  const int wr = wid >> 1, wc = wid & 1;
  const int lr = lane & 15;
  const int lg = (lane >> 4) * 4;
#pragma unroll
  for (int m = 0; m < 4; m++) {
    int rs = m0 + wr * 64 + m * 16 + lg;
    float il0 = 1.0f / L[rs], il1 = 1.0f / L[rs + 1];
    float il2 = 1.0f / L[rs + 2], il3 = 1.0f / L[rs + 3];
#pragma unroll
    for (int n = 0; n < 4; n++) {
      int col = n0 + wc * 64 + n * 16 + lr;   // v index
      f32x4 o;
      o[0] = acc[m][n][0] * il0; o[1] = acc[m][n][1] * il1;
      o[2] = acc[m][n][2] * il2; o[3] = acc[m][n][3] * il3;
      *(f32x4*)(outb + (long)col * 4096 + rs) = o;
    }
  }
}

// ---------------------------------------------------------------------------

static inline char* align256(char* p) {
  return (char*)(((uintptr_t)p + 255) & ~(uintptr_t)255);
}

extern "C" void kernel_launch(void* const* d_in, const int* in_sizes, int n_in,
                              void* d_out, int out_size, void* d_ws, size_t ws_size,
                              hipStream_t stream) {
  const float* input = (const float*)d_in[0];   // [4][1024][4096]
  const float* frame = (const float*)d_in[1];   // [4096]
  const float* Wq = (const float*)d_in[2];
  const float* bq = (const float*)d_in[3];
  const float* Wk = (const float*)d_in[4];
  const float* bk = (const float*)d_in[5];
  const float* Wv = (const float*)d_in[6];
  const float* bv = (const float*)d_in[7];
  const float* alibi = (const float*)d_in[8];
  float* out = (float*)d_out;                   // [4][2048][4096]

  const size_t NEED_BATCHED = (size_t)3072 * 1024 * 2 + 4096 +
                              4 * (4 * XB_STRIDE * 2) + 4 * SCH_STRIDE * 2 + 65536 + 2048;
  int NB = (ws_size >= NEED_BATCHED) ? 4 : 1;

  char* p = (char*)d_ws;
  __bf16* Wt = (__bf16*)p;  p += (size_t)3072 * 1024 * 2;
  float* bcat = (float*)p;  p += 3072 * 4;                    p = align256(p);
  __bf16* xb = (__bf16*)p;  p += NB * XB_STRIDE * 2;          p = align256(p);
  __bf16* Qb = (__bf16*)p;  p += NB * XB_STRIDE * 2;          p = align256(p);
  __bf16* Kb = (__bf16*)p;  p += NB * XB_STRIDE * 2;          p = align256(p);
  __bf16* Vt = (__bf16*)p;  p += NB * XB_STRIDE * 2;          p = align256(p);
  __bf16* Eb = (__bf16*)p;  p += NB * SCH_STRIDE * 2;         p = align256(p);
  float* L = (float*)p;     // NB x 4096 f32 (atomic row-sum accumulator)

  transpose_w_k<<<dim3(32, 32, 3), dim3(32, 8), 0, stream>>>(Wq, Wk, Wv, Wt);
  bcat_k<<<12, 256, 0, stream>>>(bq, bk, bv, bcat);

  for (int b0 = 0; b0 < 4; b0 += NB) {
    const float* inb = input + (size_t)b0 * XB_STRIDE;
    float* outtop = out + (size_t)b0 * OUT_STRIDE;
    float* outb = outtop + (size_t)1024 * 4096;
    transpose_x_k<<<dim3(128, 32, NB), dim3(32, 8), 0, stream>>>(inb, xb, outtop);
    zeroL_k<<<dim3(4, NB), 1024, 0, stream>>>(L);
    qkv_gemm_k<<<dim3(12, 16, NB), 512, 0, stream>>>(xb, Wt, bcat, Qb, Kb, Vt);
    qk_gemm_k<<<dim3(16, 16, NB), 512, 0, stream>>>(Qb, Kb, Eb, L, frame, alibi);
    pv_gemm_k<<<dim3(32, 8, NB), 256, 0, stream>>>(Eb, Vt, L, outb);
  }
}

// Round 24
// 393.108 us; speedup vs baseline: 1.0104x; 1.0104x over previous
//
#include <hip/hip_runtime.h>
#include <cstdint>

#define AS1 __attribute__((address_space(1)))
#define AS3 __attribute__((address_space(3)))

typedef __bf16 bf16x8 __attribute__((ext_vector_type(8)));
typedef __bf16 bf16x4 __attribute__((ext_vector_type(4)));
typedef float  f32x4  __attribute__((ext_vector_type(4)));

// Per-batch element strides
#define XB_STRIDE   4194304ul   // 4096*1024 bf16 (also Qb, Kb, Vt, input-slice fp32)
#define SCH_STRIDE  16777216ul  // 4096*4096 bf16 E matrix per batch
#define OUT_STRIDE  8388608ul   // 2048*4096 fp32

// ---------------------------------------------------------------------------
// SOFTMAX (round 22, exp-direct): scores+alibi are bounded above (~<=8) and
// bf16 has fp32 RANGE, so no max-subtraction is needed: qk's epilogue writes
// E = exp(s - sig|df|) directly (masked -> 0; distant-col exp underflows to 0
// exactly like the reference's post-max exp). rowsum_k computes invL[row] =
// 1/sum(E[row][0..row]); pv scales its fp32 acc by invL in the epilogue.
// E/L == exp(s-m)/sum exp(s-m) identically. (r23's in-GEMM fused rowsum
// regressed: epilogue shfl+atomics serialize against stores; reverted.)
// ---------------------------------------------------------------------------

// input slice [1024][4096] fp32 -> xb [4096][1024] bf16 (tiled transpose),
// FUSED with the fp32 identity copy into the output top-half (r15-verified).
__global__ void transpose_x_k(const float* __restrict__ in, __bf16* __restrict__ out,
                              float* __restrict__ outtop) {
  in     += (size_t)blockIdx.z * XB_STRIDE;
  out    += (size_t)blockIdx.z * XB_STRIDE;
  outtop += (size_t)blockIdx.z * OUT_STRIDE;
  __shared__ float t[32][33];
  int s0 = blockIdx.x * 32, c0 = blockIdx.y * 32;
  int tx = threadIdx.x, ty = threadIdx.y;
#pragma unroll
  for (int i = 0; i < 4; i++) {
    int idx = (c0 + ty + i * 8) * 4096 + s0 + tx;
    float v = in[idx];
    t[ty + i * 8][tx] = v;
    outtop[idx] = v;                   // fp32 passthrough to out[b][c][s], c<1024
  }
  __syncthreads();
#pragma unroll
  for (int i = 0; i < 4; i++)
    out[(s0 + ty + i * 8) * 1024 + c0 + tx] = (__bf16)t[tx][ty + i * 8];
}

// Wq/Wk/Wv [1024][1024] fp32 -> Wt [3072][1024] bf16 transposed, Q slice pre-scaled 1/32
__global__ void transpose_w_k(const float* __restrict__ Wq, const float* __restrict__ Wk,
                              const float* __restrict__ Wv, __bf16* __restrict__ Wt) {
  __shared__ float t[32][33];
  int sel = blockIdx.z;
  const float* W = sel == 0 ? Wq : (sel == 1 ? Wk : Wv);
  float scale = sel == 0 ? 0.03125f : 1.0f;
  int n0 = blockIdx.x * 32, c0 = blockIdx.y * 32;
  int tx = threadIdx.x, ty = threadIdx.y;
#pragma unroll
  for (int i = 0; i < 4; i++)
    t[ty + i * 8][tx] = W[(c0 + ty + i * 8) * 1024 + n0 + tx];
  __syncthreads();
#pragma unroll
  for (int i = 0; i < 4; i++)
    Wt[(sel * 1024 + n0 + ty + i * 8) * 1024 + c0 + tx] = (__bf16)(t[tx][ty + i * 8] * scale);
}

__global__ void bcat_k(const float* __restrict__ bq, const float* __restrict__ bk,
                       const float* __restrict__ bv, float* __restrict__ bcat) {
  int n = blockIdx.x * 256 + threadIdx.x;       // 3072 total
  float v = n < 1024 ? bq[n] * 0.03125f : (n < 2048 ? bk[n - 1024] : bv[n - 2048]);
  bcat[n] = v;
}

// ---------------------------------------------------------------------------
// 256x256 BK=64 streaming GEMM core (round 10; bank-conflict-free swizzle,
// counted vmcnt, 2 barriers/K-tile). Unchanged.
// ---------------------------------------------------------------------------
template<int MH, int NH>
__device__ __forceinline__ void mf_quad(f32x4 (&acc)[8][4], bf16x8 (&aR)[4][2],
                                        bf16x8 (&br)[2][2]) {
#pragma unroll
  for (int q = 0; q < 4; q++)
#pragma unroll
    for (int r = 0; r < 2; r++) {
      acc[MH * 4 + q][NH * 2 + r] = __builtin_amdgcn_mfma_f32_16x16x32_bf16(
          aR[q][0], br[r][0], acc[MH * 4 + q][NH * 2 + r], 0, 0, 0);
      acc[MH * 4 + q][NH * 2 + r] = __builtin_amdgcn_mfma_f32_16x16x32_bf16(
          aR[q][1], br[r][1], acc[MH * 4 + q][NH * 2 + r], 0, 0, 0);
    }
}

__device__ __forceinline__ void gemm256_core(const __bf16* __restrict__ A, int lda, int m0,
                                             const __bf16* __restrict__ B, int ldb, int n0,
                                             __bf16* lds, f32x4 (&acc)[8][4]) {
  const int tid = threadIdx.x;
  const int l = tid & 63;
  const int w = tid >> 6;
  const int wm = w >> 2, wn = w & 3;
  const int lr = l & 15, kg = l >> 4;
  const int lrow = l >> 3;
  const int scol = ((l & 7) ^ lrow) << 3;
  const int xorv = (lr & 7) << 4;
  const int cc0 = (kg << 4) ^ xorv;
  const int cc1 = (64 | (kg << 4)) ^ xorv;
  const int ch = w * 2;
  const char* ldsA = (const char*)lds + wm * 16384;
  const char* ldsB = (const char*)lds + 32768 + (wn >> 1) * 16384;
  const int browb = (wn & 1) * 64;

#define STG8(PTR, LD, BASE0, H, TT, JB, OPOFF) do {                                              \
    const __bf16* sp_ = (PTR) + (size_t)((BASE0) + (H) * 128 + ch * 8 + lrow) * (LD) +           \
                        (TT) * 64 + scol;                                                        \
    __bf16* dp_ = lds + ((JB) * 32768 + (OPOFF) + (H) * 8192 + ch * 512);                        \
    __builtin_amdgcn_global_load_lds((const AS1 void*)sp_,                   (AS3 void*)dp_,         16, 0, 0); \
    __builtin_amdgcn_global_load_lds((const AS1 void*)(sp_ + (size_t)8 * (LD)), (AS3 void*)(dp_ + 512), 16, 0, 0); \
  } while (0)
#define STGA(H, TT, JB) STG8(A, lda, m0, H, TT, JB, 0)
#define STGB(H, TT, JB) STG8(B, ldb, n0, H, TT, JB, 16384)
#define LDAF(dst, MH_, Q_) do {                                                                  \
    const char* p_ = ldsA + jbyte + ((MH_) * 64 + (Q_) * 16 + lr) * 128;                         \
    (dst)[0] = *(const bf16x8*)(p_ + cc0);                                                       \
    (dst)[1] = *(const bf16x8*)(p_ + cc1);                                                       \
  } while (0)
#define LDBF(dst, NH_, R_) do {                                                                  \
    const char* p_ = ldsB + jbyte + (browb + ((NH_) * 2 + (R_)) * 16 + lr) * 128;                \
    (dst)[0] = *(const bf16x8*)(p_ + cc0);                                                       \
    (dst)[1] = *(const bf16x8*)(p_ + cc1);                                                       \
  } while (0)

  STGA(0, 0, 0); STGA(1, 0, 0); STGB(0, 0, 0); STGB(1, 0, 0);
  STGB(0, 1, 1); STGA(0, 1, 1);
  asm volatile("s_waitcnt vmcnt(4)" ::: "memory");
  __builtin_amdgcn_sched_barrier(0);
  __builtin_amdgcn_s_barrier();

  bf16x8 aR[4][2], b0r[2][2], b1r[2][2];
  for (int t = 0; t < 16; ++t) {
    const int j = t & 1, jo = j ^ 1;
    const int jbyte = j * 65536;

#pragma unroll
    for (int q = 0; q < 4; q++) LDAF(aR[q], 0, q);
#pragma unroll
    for (int r = 0; r < 2; r++) LDBF(b0r[r], 0, r);
#pragma unroll
    for (int r = 0; r < 2; r++) LDBF(b1r[r], 1, r);
    if (t < 15) { STGA(1, t + 1, jo); STGB(1, t + 1, jo); }

    __builtin_amdgcn_s_setprio(1);
    mf_quad<0, 0>(acc, aR, b0r);
    mf_quad<0, 1>(acc, aR, b1r);
    __builtin_amdgcn_s_setprio(0);

#pragma unroll
    for (int q = 0; q < 4; q++) LDAF(aR[q], 1, q);
    __builtin_amdgcn_s_setprio(1);
    mf_quad<1, 1>(acc, aR, b1r);
    __builtin_amdgcn_s_setprio(0);

    asm volatile("s_waitcnt lgkmcnt(0)" ::: "memory");
    __builtin_amdgcn_sched_barrier(0);
    __builtin_amdgcn_s_barrier();
    if (t < 14) { STGB(0, t + 2, j); STGA(0, t + 2, j); }

    __builtin_amdgcn_s_setprio(1);
    mf_quad<1, 0>(acc, aR, b0r);
    __builtin_amdgcn_s_setprio(0);

    if (t < 14) asm volatile("s_waitcnt vmcnt(4)" ::: "memory");
    else        asm volatile("s_waitcnt vmcnt(0)" ::: "memory");
    __builtin_amdgcn_sched_barrier(0);
    __builtin_amdgcn_s_barrier();
  }
#undef STG8
#undef STGA
#undef STGB
#undef LDAF
#undef LDBF
}

// ---------------------------------------------------------------------------
// QKV fused projection (batched z), 256x256 streaming: [4096 x 3072] = xb @ Wt^T
__global__ void __launch_bounds__(512, 1)
qkv_gemm_k(const __bf16* __restrict__ xb, const __bf16* __restrict__ Wt,
           const float* __restrict__ bcat, __bf16* __restrict__ Qb,
           __bf16* __restrict__ Kb, __bf16* __restrict__ Vt) {
  size_t zo = (size_t)blockIdx.z * XB_STRIDE;
  xb += zo; Qb += zo; Kb += zo; Vt += zo;
  __shared__ __bf16 lds[65536];   // 128 KB
  f32x4 acc[8][4] = {};
  int m0 = blockIdx.y * 256, n0 = blockIdx.x * 256;
  gemm256_core(xb, 1024, m0, Wt, 1024, n0, lds, acc);

  const int l = threadIdx.x & 63;
  const int w = threadIdx.x >> 6;
  const int wm = w >> 2, wn = w & 3;
  const int lr = l & 15;
  const int lg = (l >> 4) * 4;
#pragma unroll
  for (int am = 0; am < 8; am++) {
    int rs = m0 + wm * 128 + am * 16 + lg;
#pragma unroll
    for (int an = 0; an < 4; an++) {
      int col = n0 + wn * 64 + an * 16 + lr;
      float bias = bcat[col];
      if (col < 1024) {
#pragma unroll
        for (int r = 0; r < 4; r++)
          Qb[(rs + r) * 1024 + col] = (__bf16)(acc[am][an][r] + bias);
      } else if (col < 2048) {
#pragma unroll
        for (int r = 0; r < 4; r++)
          Kb[(rs + r) * 1024 + (col - 1024)] = (__bf16)(acc[am][an][r] + bias);
      } else {
        bf16x4 t4;
#pragma unroll
        for (int r = 0; r < 4; r++) t4[r] = (__bf16)(acc[am][an][r] + bias);
        *(bf16x4*)(Vt + (size_t)(col - 2048) * 4096 + rs) = t4;
      }
    }
  }
}

// ---------------------------------------------------------------------------
// QK^T + exp-direct softmax numerator (batched z): epilogue applies the
// causal mask + alibi and writes E = exp(s - sig|df|) as bf16 (masked -> 0).
// No cross-lane reductions (lane-local). Upper-tri 256-tiles skipped.
__global__ void __launch_bounds__(512, 1)
qk_gemm_k(const __bf16* __restrict__ Qb, const __bf16* __restrict__ Kb,
          __bf16* __restrict__ Eb, const float* __restrict__ frame,
          const float* __restrict__ alibi_p) {
  if (blockIdx.x > blockIdx.y) return;
  size_t zo = (size_t)blockIdx.z * XB_STRIDE;
  Qb += zo; Kb += zo;
  Eb += (size_t)blockIdx.z * SCH_STRIDE;
  __shared__ __bf16 lds[65536];   // 128 KB
  f32x4 acc[8][4] = {};
  int m0 = blockIdx.y * 256, n0 = blockIdx.x * 256;
  gemm256_core(Qb, 1024, m0, Kb, 1024, n0, lds, acc);

  const int l = threadIdx.x & 63;
  const int w = threadIdx.x >> 6;
  const int wm = w >> 2, wn = w & 3;
  const int lr = l & 15;
  const int lg = (l >> 4) * 4;
  float sig = 1.0f / (1.0f + __expf(-alibi_p[0]));
  float fc[4];
#pragma unroll
  for (int an = 0; an < 4; an++) fc[an] = frame[n0 + wn * 64 + an * 16 + lr];
#pragma unroll
  for (int am = 0; am < 8; am++) {
    int rs = m0 + wm * 128 + am * 16 + lg;
    float fr0 = frame[rs], fr1 = frame[rs + 1], fr2 = frame[rs + 2], fr3 = frame[rs + 3];
    float frr[4] = {fr0, fr1, fr2, fr3};
#pragma unroll
    for (int an = 0; an < 4; an++) {
      int col = n0 + wn * 64 + an * 16 + lr;
#pragma unroll
      for (int r = 0; r < 4; r++) {
        int row = rs + r;
        float e = (col <= row) ? __expf(acc[am][an][r] - sig * fabsf(fc[an] - frr[r])) : 0.0f;
        Eb[(size_t)row * 4096 + col] = (__bf16)e;
      }
    }
  }
}

// ---------------------------------------------------------------------------
// rowsum: invL[row] = 1 / sum_{t<=row} E[row][t]. Wave per row (4 waves/block).
// Masked positions within the final chunk are zeros (written by qk), so the
// chunk-granular bound is safe.
__global__ void rowsum_k(const __bf16* __restrict__ Eb, float* __restrict__ invL) {
  Eb   += (size_t)blockIdx.y * SCH_STRIDE;
  invL += (size_t)blockIdx.y * 4096;
  int w = threadIdx.x >> 6, lane = threadIdx.x & 63;
  int row = blockIdx.x * 4 + w;
  const bf16x8* er = (const bf16x8*)(Eb + (size_t)row * 4096);
  int nh = (row + 8) >> 3;            // ceil((row+1)/8) chunks
  float s = 0.0f;
  for (int i = lane; i < nh; i += 64) {
    bf16x8 v = er[i];
#pragma unroll
    for (int e = 0; e < 8; e++) s += (float)v[e];
  }
#pragma unroll
  for (int o = 32; o; o >>= 1) s += __shfl_xor(s, o, 64);
  if (lane == 0) invL[row] = 1.0f / s;
}

// ---------------------------------------------------------------------------
// 128x128 depth-2 pipelined core (round-6), kept for PV.
__device__ __forceinline__ void gemm128_core(const __bf16* __restrict__ A, int lda, int m0,
                                             const __bf16* __restrict__ B, int ldb, int n0,
                                             int nt, __bf16 (*As)[4096], __bf16 (*Bs)[4096],
                                             f32x4 acc[4][4]) {
  const int tid = threadIdx.x;
  const int lane = tid & 63;
  const int wid = tid >> 6;
  const int wr = wid >> 1, wc = wid & 1;
  const int lr = lane & 15;
  const int lk = (((lane >> 4) ^ (lane & 3)) << 3);
  const int srow = tid >> 2;
  const int skq = (((tid & 3) ^ (srow & 3)) << 3);
  const __bf16* ga = A + (long)(m0 + srow) * lda + skq;
  const __bf16* gb = B + (long)(n0 + srow) * ldb + skq;

#define STAGE(t, j) do {                                                                                             \
    int k0_ = (t) * 32;                                                                                              \
    __builtin_amdgcn_global_load_lds((const AS1 void*)(ga + k0_),            (AS3 void*)(As[j] + tid * 8),        16, 0, 0); \
    __builtin_amdgcn_global_load_lds((const AS1 void*)(ga + k0_ + 64 * lda), (AS3 void*)(As[j] + tid * 8 + 2048), 16, 0, 0); \
    __builtin_amdgcn_global_load_lds((const AS1 void*)(gb + k0_),            (AS3 void*)(Bs[j] + tid * 8),        16, 0, 0); \
    __builtin_amdgcn_global_load_lds((const AS1 void*)(gb + k0_ + 64 * ldb), (AS3 void*)(Bs[j] + tid * 8 + 2048), 16, 0, 0); \
  } while (0)

  STAGE(0, 0);
  if (nt > 1) STAGE(1, 1);

  for (int t = 0; t < nt; ++t) {
    const int j = t & 1;
    if (t + 1 < nt) asm volatile("s_waitcnt vmcnt(4)" ::: "memory");
    else            asm volatile("s_waitcnt vmcnt(0)" ::: "memory");
    __builtin_amdgcn_s_barrier();
    __builtin_amdgcn_sched_barrier(0);

    bf16x8 af[4], bfr[4];
#pragma unroll
    for (int m = 0; m < 4; m++)
      af[m] = *(const bf16x8*)(As[j] + (wr * 64 + m * 16 + lr) * 32 + lk);
#pragma unroll
    for (int n = 0; n < 4; n++)
      bfr[n] = *(const bf16x8*)(Bs[j] + (wc * 64 + n * 16 + lr) * 32 + lk);
#pragma unroll
    for (int m = 0; m < 4; m++)
#pragma unroll
      for (int n = 0; n < 4; n++)
        acc[m][n] = __builtin_amdgcn_mfma_f32_16x16x32_bf16(af[m], bfr[n], acc[m][n], 0, 0, 0);

    asm volatile("s_waitcnt lgkmcnt(0)" ::: "memory");
    __builtin_amdgcn_sched_barrier(0);
    __builtin_amdgcn_s_barrier();
    __builtin_amdgcn_sched_barrier(0);
    if (t + 2 < nt) STAGE(t + 2, j);
  }
#undef STAGE
}

// ---------------------------------------------------------------------------
// PV (batched z): out[v][s] = (1/L_s) * sum_{t<=s} E[s,t] * Vt[v,t]; 128^2
// core; invL applied to the fp32 acc in the epilogue (exact softmax).
// Grid (32, 8, z): XCD grouping + depth reflection (round-9 win). E stride 4096.
__global__ void pv_gemm_k(const __bf16* __restrict__ E, const __bf16* __restrict__ Vt,
                          const float* __restrict__ invL, float* __restrict__ outb) {
  int z = blockIdx.z;
  int mi = (z & 1) ? blockIdx.x : 31 - blockIdx.x;   // depth reflection
  int n0 = blockIdx.y * 128;
  E    += (size_t)z * SCH_STRIDE;
  Vt   += (size_t)z * XB_STRIDE;
  invL += (size_t)z * 4096;
  outb += (size_t)z * OUT_STRIDE;
  __shared__ __bf16 As[2][4096], Bs[2][4096];
  f32x4 acc[4][4] = {};
  int m0 = mi * 128;
  gemm128_core(E, 4096, m0, Vt, 4096, n0, (m0 + 128) / 32, As, Bs, acc);

  const int lane = threadIdx.x & 63;
  const int wid = threadIdx.x >> 6;
  const int wr = wid >> 1, wc = wid & 1;
  const int lr = lane & 15;
  const int lg = (lane >> 4) * 4;
#pragma unroll
  for (int m = 0; m < 4; m++) {
    int rs = m0 + wr * 64 + m * 16 + lg;
    float il0 = invL[rs], il1 = invL[rs + 1], il2 = invL[rs + 2], il3 = invL[rs + 3];
#pragma unroll
    for (int n = 0; n < 4; n++) {
      int col = n0 + wc * 64 + n * 16 + lr;   // v index
      f32x4 o;
      o[0] = acc[m][n][0] * il0; o[1] = acc[m][n][1] * il1;
      o[2] = acc[m][n][2] * il2; o[3] = acc[m][n][3] * il3;
      *(f32x4*)(outb + (long)col * 4096 + rs) = o;
    }
  }
}

// ---------------------------------------------------------------------------

static inline char* align256(char* p) {
  return (char*)(((uintptr_t)p + 255) & ~(uintptr_t)255);
}

extern "C" void kernel_launch(void* const* d_in, const int* in_sizes, int n_in,
                              void* d_out, int out_size, void* d_ws, size_t ws_size,
                              hipStream_t stream) {
  const float* input = (const float*)d_in[0];   // [4][1024][4096]
  const float* frame = (const float*)d_in[1];   // [4096]
  const float* Wq = (const float*)d_in[2];
  const float* bq = (const float*)d_in[3];
  const float* Wk = (const float*)d_in[4];
  const float* bk = (const float*)d_in[5];
  const float* Wv = (const float*)d_in[6];
  const float* bv = (const float*)d_in[7];
  const float* alibi = (const float*)d_in[8];
  float* out = (float*)d_out;                   // [4][2048][4096]

  const size_t NEED_BATCHED = (size_t)3072 * 1024 * 2 + 4096 +
                              4 * (4 * XB_STRIDE * 2) + 4 * SCH_STRIDE * 2 + 65536 + 2048;
  int NB = (ws_size >= NEED_BATCHED) ? 4 : 1;

  char* p = (char*)d_ws;
  __bf16* Wt = (__bf16*)p;  p += (size_t)3072 * 1024 * 2;
  float* bcat = (float*)p;  p += 3072 * 4;                    p = align256(p);
  __bf16* xb = (__bf16*)p;  p += NB * XB_STRIDE * 2;          p = align256(p);
  __bf16* Qb = (__bf16*)p;  p += NB * XB_STRIDE * 2;          p = align256(p);
  __bf16* Kb = (__bf16*)p;  p += NB * XB_STRIDE * 2;          p = align256(p);
  __bf16* Vt = (__bf16*)p;  p += NB * XB_STRIDE * 2;          p = align256(p);
  __bf16* Eb = (__bf16*)p;  p += NB * SCH_STRIDE * 2;         p = align256(p);
  float* invL = (float*)p;  // NB x 4096 f32

  transpose_w_k<<<dim3(32, 32, 3), dim3(32, 8), 0, stream>>>(Wq, Wk, Wv, Wt);
  bcat_k<<<12, 256, 0, stream>>>(bq, bk, bv, bcat);

  for (int b0 = 0; b0 < 4; b0 += NB) {
    const float* inb = input + (size_t)b0 * XB_STRIDE;
    float* outtop = out + (size_t)b0 * OUT_STRIDE;
    float* outb = outtop + (size_t)1024 * 4096;
    transpose_x_k<<<dim3(128, 32, NB), dim3(32, 8), 0, stream>>>(inb, xb, outtop);
    qkv_gemm_k<<<dim3(12, 16, NB), 512, 0, stream>>>(xb, Wt, bcat, Qb, Kb, Vt);
    qk_gemm_k<<<dim3(16, 16, NB), 512, 0, stream>>>(Qb, Kb, Eb, frame, alibi);
    rowsum_k<<<dim3(1024, NB), 256, 0, stream>>>(Eb, invL);
    pv_gemm_k<<<dim3(32, 8, NB), 256, 0, stream>>>(Eb, Vt, invL, outb);
  }
}